// Round 3
// baseline (246.285 us; speedup 1.0000x reference)
//
#include <hip/hip_runtime.h>
#include <math.h>

#define BB 8
#define CC 64
#define OO 64
#define HH 128
#define WW 128
#define HW (HH*WW)              // 16384
#define NPIX (BB*HW)            // 131072

typedef __bf16 bf16x8 __attribute__((ext_vector_type(8)));
typedef float floatx4 __attribute__((ext_vector_type(4)));
typedef float f32x2 __attribute__((ext_vector_type(2)));
typedef unsigned short ushort_t;

// Workspace layout (bytes):
//  xt : bf16 NHWC [B][H][W][64]        16777216
//  om : fp32 [NPIX][28]                14680064
//  wt : bf16 [64][576]  (o, tap*64+c)     73728
//  wb : bf16 [32][576]  (o27pad, k)       36864
#define XT_BYTES  16777216
#define OM_BYTES  14680064
#define WT_BYTES  73728

__device__ __forceinline__ unsigned short f2b(float f) {
    unsigned u = __float_as_uint(f);
    u += 0x7fffu + ((u >> 16) & 1u);       // round-to-nearest-even
    return (unsigned short)(u >> 16);
}

// packed 2xf32 -> 2xbf16 in one VALU op (no builtin on gfx950; asm per guide)
__device__ __forceinline__ unsigned cvt_pk_bf16(float lo, float hi) {
    unsigned r;
    asm("v_cvt_pk_bf16_f32 %0, %1, %2" : "=v"(r) : "v"(lo), "v"(hi));
    return r;
}

__device__ __forceinline__ f32x2 pk_fma(f32x2 a, f32x2 b, f32x2 c) {
    f32x2 d;
    asm("v_pk_fma_f32 %0, %1, %2, %3" : "=v"(d) : "v"(a), "v"(b), "v"(c));
    return d;
}

__device__ __forceinline__ f32x2 pk_mul(f32x2 a, f32x2 b) {
    f32x2 d;
    asm("v_pk_mul_f32 %0, %1, %2" : "=v"(d) : "v"(a), "v"(b));
    return d;
}

// ---------------------------------------------------------------------------
// Kernel 1: NCHW fp32 -> NHWC bf16 transpose, packed 4B stores
// ---------------------------------------------------------------------------
__global__ __launch_bounds__(256) void transpose_kernel(
    const float* __restrict__ x, ushort_t* __restrict__ xt)
{
    __shared__ float tile[64][33];
    int bh = blockIdx.x;
    int w0 = blockIdx.y * 32;
    int b  = bh >> 7;
    int h  = bh & 127;
    int t  = threadIdx.x;
    int tx = t & 31;
    int ty = t >> 5;

    #pragma unroll
    for (int j = 0; j < 8; ++j) {
        int c = ty * 8 + j;
        tile[c][tx] = x[(((size_t)(b*CC + c))*HH + h)*WW + (w0 + tx)];
    }
    __syncthreads();
    #pragma unroll
    for (int j = 0; j < 4; ++j) {
        int w  = ty + 8*j;
        int cp = tx;
        unsigned u = cvt_pk_bf16(tile[2*cp][w], tile[2*cp+1][w]);
        *(unsigned*)(xt + (((size_t)(b*HH + h))*WW + (w0 + w))*CC + 2*cp) = u;
    }
}

// ---------------------------------------------------------------------------
// Kernel 2: weight repack to bf16
// ---------------------------------------------------------------------------
__global__ __launch_bounds__(256) void repack_kernel(
    const float* __restrict__ wm, const float* __restrict__ woff,
    const float* __restrict__ wmask, ushort_t* __restrict__ wt,
    ushort_t* __restrict__ wb)
{
    int i = blockIdx.x * 256 + threadIdx.x;
    if (i < 36864) {
        int o = i / 576, k = i % 576, tap = k >> 6, c = k & 63;
        wt[i] = f2b(wm[o*576 + c*9 + tap]);
    }
    int j = i - 36864;
    if (j >= 0 && j < 18432) {
        int o = j / 576, k = j % 576, tap = k >> 6, c = k & 63;
        float v = 0.f;
        if (o < 18)      v = woff[o*576 + c*9 + tap];
        else if (o < 27) v = wmask[(o-18)*576 + c*9 + tap];
        wb[j] = f2b(v);
    }
}

// ---------------------------------------------------------------------------
// Kernel 3: conv3x3 -> 18 offsets + 9 sigmoid masks, bf16 MFMA, 16x16 tiles
// ---------------------------------------------------------------------------
__global__ __launch_bounds__(256) void conv27_kernel(
    const ushort_t* __restrict__ xt, const ushort_t* __restrict__ wb,
    const float* __restrict__ boff, const float* __restrict__ bmsk,
    float* __restrict__ om)
{
    __shared__ ushort_t win[18*18*72];
    int bid = blockIdx.x;
    int b  = bid >> 6;
    int th = (bid >> 3) & 7;
    int tw = bid & 7;
    int h0 = th * 16, w0 = tw * 16;
    int t = threadIdx.x;

    for (int idx = t; idx < 18*18*8; idx += 256) {
        int r   = idx / 144;
        int rem = idx - r*144;
        int col = rem >> 3;
        int ch  = (rem & 7) << 3;
        int y = h0 + r - 1, x = w0 + col - 1;
        uint4 val = make_uint4(0,0,0,0);
        if ((unsigned)y < (unsigned)HH && (unsigned)x < (unsigned)WW)
            val = *(const uint4*)(xt + ((((size_t)b*HH + y)*WW + x) << 6) + ch);
        *(uint4*)(win + (r*18 + col)*72 + ch) = val;
    }
    __syncthreads();

    int lane = t & 63, wv = t >> 6;
    int n = lane & 15, quad = lane >> 4;
    const ushort_t* wb0 = wb + n*576;
    const ushort_t* wb1 = wb + (16 + n)*576;

    floatx4 acc0[4], acc1[4];
    #pragma unroll
    for (int mt = 0; mt < 4; ++mt) {
        acc0[mt] = (floatx4){0.f,0.f,0.f,0.f};
        acc1[mt] = (floatx4){0.f,0.f,0.f,0.f};
    }

    #pragma unroll
    for (int s = 0; s < 18; ++s) {
        int tap  = s >> 1;
        int tr   = tap / 3, tc = tap % 3;
        int coff = (s & 1)*32 + quad*8;
        int kk = tap*64 + coff;
        bf16x8 b0 = *(const bf16x8*)(wb0 + kk);
        bf16x8 b1 = *(const bf16x8*)(wb1 + kk);
        #pragma unroll
        for (int mt = 0; mt < 4; ++mt) {
            int ty = wv*4 + mt;
            bf16x8 a = *(const bf16x8*)(win + ((ty + tr)*18 + (n + tc))*72 + coff);
            acc0[mt] = __builtin_amdgcn_mfma_f32_16x16x32_bf16(a, b0, acc0[mt], 0, 0, 0);
            acc1[mt] = __builtin_amdgcn_mfma_f32_16x16x32_bf16(a, b1, acc1[mt], 0, 0, 0);
        }
    }

    #pragma unroll
    for (int mt = 0; mt < 4; ++mt) {
        int ty = wv*4 + mt;
        #pragma unroll
        for (int r = 0; r < 4; ++r) {
            int tx = quad*4 + r;
            size_t p = ((size_t)(b*HH + h0 + ty))*WW + (w0 + tx);
            float* dst = om + p*28;
            dst[n] = acc0[mt][r] + boff[n];
            int o1 = 16 + n;
            if (o1 < 18) {
                dst[o1] = acc1[mt][r] + boff[o1];
            } else if (o1 < 27) {
                float z = acc1[mt][r] + bmsk[o1 - 18];
                dst[o1] = 1.f / (1.f + expf(-z));
            } else if (o1 == 27) {
                dst[27] = 0.f;
            }
        }
    }
}

// ---------------------------------------------------------------------------
// Kernel 4: deformable sampling + bf16 MFMA GEMM — REGISTER-DIRECT form
//
// Round-2 post-mortem: wave-private LDS round-trip (ds_write -> lgkmcnt(0)
// -> ds_read) per tap serialized each wave brutally (101us, VALUBusy 22%).
// Round-0/1's barrier convoy was 58us. Root cost in both: the LDS reshuffle
// between the sampling lane->pixel map and the MFMA A-fragment map.
//
// This round: make the two maps COINCIDE so LDS is unnecessary.
// MFMA 16x16x32 A-fragment: lane (n=lane&15, quad=lane>>4) holds
// A[pixel=n][ch = half*32 + quad*8 .. +8]. So sampling role is
// pixel = n, channel-group = quad: each lane samples exactly the 16
// channels (quad*8.. and 32+quad*8..) of pixel n that its own MFMA
// operand consumes. Sampled values go registers -> cvt_pk -> bf16x8
// fragment directly. ZERO LDS, ZERO barriers in this kernel.
// B-fragments stream from global wt (73KB, L1/L2-resident, static addrs).
// Fragment content is bit-identical to round-2's ds_read path (verified
// pass), store mapping identical to round 2.
// ---------------------------------------------------------------------------
__global__ __launch_bounds__(256, 4) void deform_kernel(
    const ushort_t* __restrict__ xt, const float* __restrict__ om,
    const ushort_t* __restrict__ wt, float* __restrict__ out)
{
    int t = threadIdx.x;
    int lane = t & 63, wv = t >> 6;
    int bid = blockIdx.x;
    int b  = bid >> 8;
    int th = (bid >> 4) & 15;
    int tw = bid & 15;
    int h0 = th * 8, w0 = tw * 8;

    int n = lane & 15, quad = lane >> 4;

    // this lane's pixel (16 px per wave = 2 rows of 8) and channel group
    int p_lin = wv*16 + n;                  // 0..63 within the 8x8 tile
    int h_a = h0 + (p_lin >> 3), w_a = w0 + (p_lin & 7);
    const float* omp = om + (((size_t)(b*HH + h_a))*WW + w_a) * 28;
    const ushort_t* xbase = xt + ((size_t)b << 20) + quad*8;   // fold ch offset
    const ushort_t* wrow  = wt + n*576 + quad*8;               // + og*9216 + k*64 (+32)

    floatx4 acc[4];                          // [o-group]: 16 px x 64 o total
    #pragma unroll
    for (int i = 0; i < 4; ++i) acc[i] = (floatx4){0.f,0.f,0.f,0.f};

    float dy = omp[0], dx = omp[1], m = omp[18];   // tap-0 params

    for (int k = 0; k < 9; ++k) {
        // prefetch next tap's params (hide om latency behind this tap's work)
        float dy_n = 0.f, dx_n = 0.f, m_n = 0.f;
        if (k < 8) { dy_n = omp[2*k + 2]; dx_n = omp[2*k + 3]; m_n = omp[19 + k]; }

        // ---------------- bilinear setup (4 lanes/px redundant) ----------------
        int kr = k / 3, kc = k - kr*3;
        float py = (float)(h_a + kr - 1) + dy;
        float px = (float)(w_a + kc - 1) + dx;
        float y0f = floorf(py), x0f = floorf(px);
        float ly = py - y0f, lx = px - x0f;
        int y0 = (int)y0f, x0 = (int)x0f, y1 = y0 + 1, x1 = x0 + 1;
        float vy0 = ((unsigned)y0 < (unsigned)HH) ? 1.f : 0.f;
        float vy1 = ((unsigned)y1 < (unsigned)HH) ? 1.f : 0.f;
        float vx0 = ((unsigned)x0 < (unsigned)WW) ? 1.f : 0.f;
        float vx1 = ((unsigned)x1 < (unsigned)WW) ? 1.f : 0.f;

        float cw[4] = { (1.f-ly)*(1.f-lx)*vy0*vx0*m,
                        (1.f-ly)*lx      *vy0*vx1*m,
                        ly*(1.f-lx)      *vy1*vx0*m,
                        ly*lx            *vy1*vx1*m };
        int ys[4] = { y0, y0, y1, y1 };
        int xs[4] = { x0, x1, x0, x1 };

        dy = dy_n; dx = dx_n; m = m_n;   // rotate pipeline regs

        // gather: 8 dwordx4 loads, all issued before any use (MLP depth 8)
        // q[2c] = ch [quad*8, +8), q[2c+1] = ch [32+quad*8, +8)
        uint4 q[8];
        #pragma unroll
        for (int cn = 0; cn < 4; ++cn) {
            int yc = min(max(ys[cn], 0), HH-1);
            int xc = min(max(xs[cn], 0), WW-1);
            const uint4* cp = (const uint4*)(xbase + (((yc << 7) + xc) << 6));
            q[2*cn]   = cp[0];
            q[2*cn+1] = cp[4];      // +64B = +32 channels
        }

        // packed fp32 corner accumulate: v2[0..3] = lo 8 ch, v2[4..7] = hi 8 ch
        f32x2 v2[8];
        {
            f32x2 w2; w2.x = cw[0]; w2.y = cw[0];
            unsigned u0[8] = { q[0].x, q[0].y, q[0].z, q[0].w,
                               q[1].x, q[1].y, q[1].z, q[1].w };
            #pragma unroll
            for (int j = 0; j < 8; ++j) {
                f32x2 f;
                f.x = __uint_as_float(u0[j] << 16);
                f.y = __uint_as_float(u0[j] & 0xffff0000u);
                v2[j] = pk_mul(f, w2);
            }
        }
        #pragma unroll
        for (int cn = 1; cn < 4; ++cn) {
            f32x2 w2; w2.x = cw[cn]; w2.y = cw[cn];
            unsigned u0[8] = { q[2*cn].x, q[2*cn].y, q[2*cn].z, q[2*cn].w,
                               q[2*cn+1].x, q[2*cn+1].y, q[2*cn+1].z, q[2*cn+1].w };
            #pragma unroll
            for (int j = 0; j < 8; ++j) {
                f32x2 f;
                f.x = __uint_as_float(u0[j] << 16);
                f.y = __uint_as_float(u0[j] & 0xffff0000u);
                v2[j] = pk_fma(f, w2, v2[j]);
            }
        }

        // pack to A-fragments in registers (no LDS): af0 = k-slice quad*8,
        // af1 = k-slice 32+quad*8 — exactly this lane's MFMA operand.
        union { uint4 u; bf16x8 v; } a0, a1;
        a0.u = make_uint4(cvt_pk_bf16(v2[0].x, v2[0].y),
                          cvt_pk_bf16(v2[1].x, v2[1].y),
                          cvt_pk_bf16(v2[2].x, v2[2].y),
                          cvt_pk_bf16(v2[3].x, v2[3].y));
        a1.u = make_uint4(cvt_pk_bf16(v2[4].x, v2[4].y),
                          cvt_pk_bf16(v2[5].x, v2[5].y),
                          cvt_pk_bf16(v2[6].x, v2[6].y),
                          cvt_pk_bf16(v2[7].x, v2[7].y));

        // ---------------- MFMA accumulate (all 64 outputs) ----------------
        #pragma unroll
        for (int og = 0; og < 4; ++og) {
            bf16x8 b0 = *(const bf16x8*)(wrow + og*(16*576) + k*64);
            acc[og] = __builtin_amdgcn_mfma_f32_16x16x32_bf16(a0.v, b0, acc[og], 0, 0, 0);
        }
        #pragma unroll
        for (int og = 0; og < 4; ++og) {
            bf16x8 b1 = *(const bf16x8*)(wrow + og*(16*576) + k*64 + 32);
            acc[og] = __builtin_amdgcn_mfma_f32_16x16x32_bf16(a1.v, b1, acc[og], 0, 0, 0);
        }
    }

    // store: out[b][o][h][w], o = og*16 + n; D row = wave-local pixel
    // px_local = quad*4 + r -> row = h0 + wv*2 + (quad>>1),
    //                          col = w0 + (quad&1)*4 + r
    int row = h0 + wv*2 + (quad >> 1);
    int col = w0 + (quad & 1)*4;
    #pragma unroll
    for (int og = 0; og < 4; ++og) {
        float* op = out + ((size_t)b*OO + (og*16 + n))*HW;
        float4 st = make_float4(acc[og][0], acc[og][1], acc[og][2], acc[og][3]);
        *(float4*)(op + row*WW + col) = st;
    }
}

// ---------------------------------------------------------------------------
extern "C" void kernel_launch(void* const* d_in, const int* in_sizes, int n_in,
                              void* d_out, int out_size, void* d_ws, size_t ws_size,
                              hipStream_t stream)
{
    const float* x      = (const float*)d_in[0];
    const float* w_main = (const float*)d_in[1];
    const float* w_off  = (const float*)d_in[2];
    const float* b_off  = (const float*)d_in[3];
    const float* w_msk  = (const float*)d_in[4];
    const float* b_msk  = (const float*)d_in[5];
    float* out = (float*)d_out;

    unsigned char* ws = (unsigned char*)d_ws;
    ushort_t* xt = (ushort_t*)ws;
    float*    om = (float*)(ws + XT_BYTES);
    ushort_t* wt = (ushort_t*)(ws + XT_BYTES + OM_BYTES);
    ushort_t* wb = (ushort_t*)(ws + XT_BYTES + OM_BYTES + WT_BYTES);

    dim3 tgrid(BB*HH, WW/32);
    transpose_kernel<<<tgrid, 256, 0, stream>>>(x, xt);

    repack_kernel<<<(36864 + 18432 + 255)/256, 256, 0, stream>>>(
        w_main, w_off, w_msk, wt, wb);

    conv27_kernel<<<NPIX/256, 256, 0, stream>>>(xt, wb, b_off, b_msk, om);

    deform_kernel<<<NPIX/64, 256, 0, stream>>>(xt, om, wt, out);
}

// Round 5
// 157.656 us; speedup vs baseline: 1.5622x; 1.5622x over previous
//
#include <hip/hip_runtime.h>
#include <math.h>

#define BB 8
#define CC 64
#define OO 64
#define HH 128
#define WW 128
#define HW (HH*WW)              // 16384
#define NPIX (BB*HW)            // 131072

typedef __bf16 bf16x8 __attribute__((ext_vector_type(8)));
typedef float floatx4 __attribute__((ext_vector_type(4)));
typedef float f32x2 __attribute__((ext_vector_type(2)));
typedef unsigned short ushort_t;

// Workspace layout (bytes):
//  xt : bf16 NHWC [B][H][W][64]        16777216
//  om : fp32 [NPIX][28]                14680064
//  wt : bf16 [64][576]  (o, tap*64+c)     73728
//  wb : bf16 [32][576]  (o27pad, k)       36864
#define XT_BYTES  16777216
#define OM_BYTES  14680064
#define WT_BYTES  73728

__device__ __forceinline__ unsigned short f2b(float f) {
    unsigned u = __float_as_uint(f);
    u += 0x7fffu + ((u >> 16) & 1u);       // round-to-nearest-even
    return (unsigned short)(u >> 16);
}

// packed 2xf32 -> 2xbf16 in one VALU op (no builtin on gfx950; asm per guide)
__device__ __forceinline__ unsigned cvt_pk_bf16(float lo, float hi) {
    unsigned r;
    asm("v_cvt_pk_bf16_f32 %0, %1, %2" : "=v"(r) : "v"(lo), "v"(hi));
    return r;
}

__device__ __forceinline__ f32x2 pk_fma(f32x2 a, f32x2 b, f32x2 c) {
    f32x2 d;
    asm("v_pk_fma_f32 %0, %1, %2, %3" : "=v"(d) : "v"(a), "v"(b), "v"(c));
    return d;
}

__device__ __forceinline__ f32x2 pk_mul(f32x2 a, f32x2 b) {
    f32x2 d;
    asm("v_pk_mul_f32 %0, %1, %2" : "=v"(d) : "v"(a), "v"(b));
    return d;
}

// ---------------------------------------------------------------------------
// Kernel 1: NCHW fp32 -> NHWC bf16 transpose, packed 4B stores
// ---------------------------------------------------------------------------
__global__ __launch_bounds__(256) void transpose_kernel(
    const float* __restrict__ x, ushort_t* __restrict__ xt)
{
    __shared__ float tile[64][33];
    int bh = blockIdx.x;
    int w0 = blockIdx.y * 32;
    int b  = bh >> 7;
    int h  = bh & 127;
    int t  = threadIdx.x;
    int tx = t & 31;
    int ty = t >> 5;

    #pragma unroll
    for (int j = 0; j < 8; ++j) {
        int c = ty * 8 + j;
        tile[c][tx] = x[(((size_t)(b*CC + c))*HH + h)*WW + (w0 + tx)];
    }
    __syncthreads();
    #pragma unroll
    for (int j = 0; j < 4; ++j) {
        int w  = ty + 8*j;
        int cp = tx;
        unsigned u = cvt_pk_bf16(tile[2*cp][w], tile[2*cp+1][w]);
        *(unsigned*)(xt + (((size_t)(b*HH + h))*WW + (w0 + w))*CC + 2*cp) = u;
    }
}

// ---------------------------------------------------------------------------
// Kernel 2: weight repack to bf16
// ---------------------------------------------------------------------------
__global__ __launch_bounds__(256) void repack_kernel(
    const float* __restrict__ wm, const float* __restrict__ woff,
    const float* __restrict__ wmask, ushort_t* __restrict__ wt,
    ushort_t* __restrict__ wb)
{
    int i = blockIdx.x * 256 + threadIdx.x;
    if (i < 36864) {
        int o = i / 576, k = i % 576, tap = k >> 6, c = k & 63;
        wt[i] = f2b(wm[o*576 + c*9 + tap]);
    }
    int j = i - 36864;
    if (j >= 0 && j < 18432) {
        int o = j / 576, k = j % 576, tap = k >> 6, c = k & 63;
        float v = 0.f;
        if (o < 18)      v = woff[o*576 + c*9 + tap];
        else if (o < 27) v = wmask[(o-18)*576 + c*9 + tap];
        wb[j] = f2b(v);
    }
}

// ---------------------------------------------------------------------------
// Kernel 3: conv3x3 -> 18 offsets + 9 sigmoid masks, bf16 MFMA, 16x16 tiles
// ---------------------------------------------------------------------------
__global__ __launch_bounds__(256) void conv27_kernel(
    const ushort_t* __restrict__ xt, const ushort_t* __restrict__ wb,
    const float* __restrict__ boff, const float* __restrict__ bmsk,
    float* __restrict__ om)
{
    __shared__ ushort_t win[18*18*72];
    int bid = blockIdx.x;
    int b  = bid >> 6;
    int th = (bid >> 3) & 7;
    int tw = bid & 7;
    int h0 = th * 16, w0 = tw * 16;
    int t = threadIdx.x;

    for (int idx = t; idx < 18*18*8; idx += 256) {
        int r   = idx / 144;
        int rem = idx - r*144;
        int col = rem >> 3;
        int ch  = (rem & 7) << 3;
        int y = h0 + r - 1, x = w0 + col - 1;
        uint4 val = make_uint4(0,0,0,0);
        if ((unsigned)y < (unsigned)HH && (unsigned)x < (unsigned)WW)
            val = *(const uint4*)(xt + ((((size_t)b*HH + y)*WW + x) << 6) + ch);
        *(uint4*)(win + (r*18 + col)*72 + ch) = val;
    }
    __syncthreads();

    int lane = t & 63, wv = t >> 6;
    int n = lane & 15, quad = lane >> 4;
    const ushort_t* wb0 = wb + n*576;
    const ushort_t* wb1 = wb + (16 + n)*576;

    floatx4 acc0[4], acc1[4];
    #pragma unroll
    for (int mt = 0; mt < 4; ++mt) {
        acc0[mt] = (floatx4){0.f,0.f,0.f,0.f};
        acc1[mt] = (floatx4){0.f,0.f,0.f,0.f};
    }

    #pragma unroll
    for (int s = 0; s < 18; ++s) {
        int tap  = s >> 1;
        int tr   = tap / 3, tc = tap % 3;
        int coff = (s & 1)*32 + quad*8;
        int kk = tap*64 + coff;
        bf16x8 b0 = *(const bf16x8*)(wb0 + kk);
        bf16x8 b1 = *(const bf16x8*)(wb1 + kk);
        #pragma unroll
        for (int mt = 0; mt < 4; ++mt) {
            int ty = wv*4 + mt;
            bf16x8 a = *(const bf16x8*)(win + ((ty + tr)*18 + (n + tc))*72 + coff);
            acc0[mt] = __builtin_amdgcn_mfma_f32_16x16x32_bf16(a, b0, acc0[mt], 0, 0, 0);
            acc1[mt] = __builtin_amdgcn_mfma_f32_16x16x32_bf16(a, b1, acc1[mt], 0, 0, 0);
        }
    }

    #pragma unroll
    for (int mt = 0; mt < 4; ++mt) {
        int ty = wv*4 + mt;
        #pragma unroll
        for (int r = 0; r < 4; ++r) {
            int tx = quad*4 + r;
            size_t p = ((size_t)(b*HH + h0 + ty))*WW + (w0 + tx);
            float* dst = om + p*28;
            dst[n] = acc0[mt][r] + boff[n];
            int o1 = 16 + n;
            if (o1 < 18) {
                dst[o1] = acc1[mt][r] + boff[o1];
            } else if (o1 < 27) {
                float z = acc1[mt][r] + bmsk[o1 - 18];
                dst[o1] = 1.f / (1.f + expf(-z));
            } else if (o1 == 27) {
                dst[27] = 0.f;
            }
        }
    }
}

// ---------------------------------------------------------------------------
// Kernel 4: deformable sampling + bf16 MFMA GEMM — 3-TAP PHASED form
//
// (Round-4 was an infra failure; this is the round-3 design, unmeasured.)
//
// Round-2/3 post-mortems: both redesigns that abandoned the round-0/1
// structure regressed badly. Load-bearing features of that structure:
// 4-lanes-per-pixel gather (4-lane clusters read 128B contiguous) and
// LDS-staged A-fragments. The actual waste in round-1: 9 barrier convoys
// per block (one per tap, each exposing full gather latency to all 4
// waves) and per-tap global B-fragment loads on the phase-B path.
//
// Schedule-only change on the proven structure:
//  - 3 taps per phase, single LDS buffer [64 px][3*64 + 8 pad] (25.6KB).
//    {sample 3 taps -> bar -> 24 MFMAs -> bar} x3 = 5 barriers (was 9),
//    and each phase-A has 3 taps of gathers to overlap within the wave.
//  - Phase's 6 weight B-frags preloaded into regs at top of phase A
//    (loads land under the gathers); phase B = pure ds_read + MFMA.
//  - Row pad to 400B (100 banks = 4 mod 32): uniform bank spread on both
//    ds_write_b128 and ds_read_b128.
//  - Everything else (lane maps, gather code, pack, store) = round-1.
// ---------------------------------------------------------------------------
#define SROW 200   // ushorts per pixel row: 3 taps * 64 ch + 8 pad

__global__ __launch_bounds__(256, 3) void deform_kernel(
    const ushort_t* __restrict__ xt, const float* __restrict__ om,
    const ushort_t* __restrict__ wt, float* __restrict__ out)
{
    __shared__ ushort_t samp[64*SROW];   // 25600 B, single-buffered

    int t = threadIdx.x;
    int lane = t & 63, wv = t >> 6;
    int bid = blockIdx.x;
    int b  = bid >> 8;
    int th = (bid >> 4) & 15;
    int tw = bid & 15;
    int h0 = th * 8, w0 = tw * 8;

    // sampling role: 4 threads/pixel, 16 ch each; 8x8 pixel tile
    int pa = t >> 2, cg = t & 3;
    int ph = pa >> 3, pw = pa & 7;
    int h_a = h0 + ph, w_a = w0 + pw;
    const float* omp = om + (((size_t)(b*HH + h_a))*WW + w_a) * 28;
    const ushort_t* xbase = xt + ((size_t)b << 20);

    // MFMA role
    int n = lane & 15, quad = lane >> 4;
    floatx4 acc[4];
    #pragma unroll
    for (int i = 0; i < 4; ++i) acc[i] = (floatx4){0.f,0.f,0.f,0.f};
    const ushort_t* wrow = wt + (wv*16 + n)*576 + quad*8;

    // params for phase 0 (taps 0..2)
    float dyv[3], dxv[3], mv[3];
    #pragma unroll
    for (int j = 0; j < 3; ++j) {
        dyv[j] = omp[2*j]; dxv[j] = omp[2*j+1]; mv[j] = omp[18+j];
    }

    #pragma unroll
    for (int p = 0; p < 3; ++p) {
        // preload this phase's 6 weight B-frags (complete under the gathers)
        bf16x8 wf[6];
        #pragma unroll
        for (int s = 0; s < 6; ++s)
            wf[s] = *(const bf16x8*)(wrow + (p*6 + s)*32);   // tap*64+half*32

        // ---------------- phase A: sample taps 3p..3p+2 ----------------
        #pragma unroll
        for (int kk = 0; kk < 3; ++kk) {
            // k = 3p + kk  =>  kr = p, kc = kk
            float py = (float)(h_a + p  - 1) + dyv[kk];
            float px = (float)(w_a + kk - 1) + dxv[kk];
            float y0f = floorf(py), x0f = floorf(px);
            float ly = py - y0f, lx = px - x0f;
            int y0 = (int)y0f, x0 = (int)x0f, y1 = y0 + 1, x1 = x0 + 1;
            float vy0 = ((unsigned)y0 < (unsigned)HH) ? 1.f : 0.f;
            float vy1 = ((unsigned)y1 < (unsigned)HH) ? 1.f : 0.f;
            float vx0 = ((unsigned)x0 < (unsigned)WW) ? 1.f : 0.f;
            float vx1 = ((unsigned)x1 < (unsigned)WW) ? 1.f : 0.f;
            float m   = mv[kk];

            float cw[4] = { (1.f-ly)*(1.f-lx)*vy0*vx0*m,
                            (1.f-ly)*lx      *vy0*vx1*m,
                            ly*(1.f-lx)      *vy1*vx0*m,
                            ly*lx            *vy1*vx1*m };
            int ys[4] = { y0, y0, y1, y1 };
            int xs[4] = { x0, x1, x0, x1 };

            // gather: 8 dwordx4, 4-lane clusters contiguous 128B (proven map)
            uint4 q[8];
            #pragma unroll
            for (int cn = 0; cn < 4; ++cn) {
                int yc = min(max(ys[cn], 0), HH-1);
                int xc = min(max(xs[cn], 0), WW-1);
                const uint4* cp = (const uint4*)(xbase + (((yc << 7) + xc) << 6) + cg*16);
                q[2*cn]   = cp[0];
                q[2*cn+1] = cp[1];
            }

            // packed fp32 corner accumulate
            f32x2 v2[8];
            {
                f32x2 w2; w2.x = cw[0]; w2.y = cw[0];
                unsigned u0[8] = { q[0].x, q[0].y, q[0].z, q[0].w,
                                   q[1].x, q[1].y, q[1].z, q[1].w };
                #pragma unroll
                for (int j = 0; j < 8; ++j) {
                    f32x2 f;
                    f.x = __uint_as_float(u0[j] << 16);
                    f.y = __uint_as_float(u0[j] & 0xffff0000u);
                    v2[j] = pk_mul(f, w2);
                }
            }
            #pragma unroll
            for (int cn = 1; cn < 4; ++cn) {
                f32x2 w2; w2.x = cw[cn]; w2.y = cw[cn];
                unsigned u0[8] = { q[2*cn].x, q[2*cn].y, q[2*cn].z, q[2*cn].w,
                                   q[2*cn+1].x, q[2*cn+1].y, q[2*cn+1].z, q[2*cn+1].w };
                #pragma unroll
                for (int j = 0; j < 8; ++j) {
                    f32x2 f;
                    f.x = __uint_as_float(u0[j] << 16);
                    f.y = __uint_as_float(u0[j] & 0xffff0000u);
                    v2[j] = pk_fma(f, w2, v2[j]);
                }
            }

            // pack 16 fp32 -> bf16, write 32B to samp[pa][kk*64 + cg*16]
            {
                unsigned uu[8];
                #pragma unroll
                for (int j = 0; j < 8; ++j)
                    uu[j] = cvt_pk_bf16(v2[j].x, v2[j].y);
                uint4* dst = (uint4*)(samp + pa*SROW + kk*64 + cg*16);
                dst[0] = make_uint4(uu[0], uu[1], uu[2], uu[3]);
                dst[1] = make_uint4(uu[4], uu[5], uu[6], uu[7]);
            }
        }

        // prefetch next phase's params before the barrier
        float dyn_[3], dxn_[3], mn_[3];
        if (p < 2) {
            #pragma unroll
            for (int j = 0; j < 3; ++j) {
                int k2 = 3*(p+1) + j;
                dyn_[j] = omp[2*k2]; dxn_[j] = omp[2*k2+1]; mn_[j] = omp[18+k2];
            }
        }

        __syncthreads();

        // ---------------- phase B: 24 MFMAs from LDS + reg weights ----------------
        #pragma unroll
        for (int kk = 0; kk < 3; ++kk) {
            #pragma unroll
            for (int half = 0; half < 2; ++half) {
                bf16x8 bfrag = wf[kk*2 + half];
                #pragma unroll
                for (int mt = 0; mt < 4; ++mt) {
                    bf16x8 afrag = *(const bf16x8*)(samp + (mt*16 + n)*SROW
                                                    + kk*64 + half*32 + quad*8);
                    acc[mt] = __builtin_amdgcn_mfma_f32_16x16x32_bf16(
                                  afrag, bfrag, acc[mt], 0, 0, 0);
                }
            }
        }

        if (p < 2) {
            __syncthreads();   // WAR: next phase A overwrites the buffer
            #pragma unroll
            for (int j = 0; j < 3; ++j) {
                dyv[j] = dyn_[j]; dxv[j] = dxn_[j]; mv[j] = mn_[j];
            }
        }
    }

    // store: out[b][o][h][w], o = wv*16 + n; D rows = local pixel id
    // p_local = mt*16 + quad*4 + r -> row = h0 + mt*2 + (quad>>1),
    //                                  col = w0 + (quad&1)*4 + r
    float* op = out + ((size_t)b*OO + (wv*16 + n))*HW;
    #pragma unroll
    for (int mt = 0; mt < 4; ++mt) {
        int row = h0 + mt*2 + (quad >> 1);
        int col = w0 + (quad & 1)*4;
        float4 st = make_float4(acc[mt][0], acc[mt][1], acc[mt][2], acc[mt][3]);
        *(float4*)(op + row*WW + col) = st;
    }
}

// ---------------------------------------------------------------------------
extern "C" void kernel_launch(void* const* d_in, const int* in_sizes, int n_in,
                              void* d_out, int out_size, void* d_ws, size_t ws_size,
                              hipStream_t stream)
{
    const float* x      = (const float*)d_in[0];
    const float* w_main = (const float*)d_in[1];
    const float* w_off  = (const float*)d_in[2];
    const float* b_off  = (const float*)d_in[3];
    const float* w_msk  = (const float*)d_in[4];
    const float* b_msk  = (const float*)d_in[5];
    float* out = (float*)d_out;

    unsigned char* ws = (unsigned char*)d_ws;
    ushort_t* xt = (ushort_t*)ws;
    float*    om = (float*)(ws + XT_BYTES);
    ushort_t* wt = (ushort_t*)(ws + XT_BYTES + OM_BYTES);
    ushort_t* wb = (ushort_t*)(ws + XT_BYTES + OM_BYTES + WT_BYTES);

    dim3 tgrid(BB*HH, WW/32);
    transpose_kernel<<<tgrid, 256, 0, stream>>>(x, xt);

    repack_kernel<<<(36864 + 18432 + 255)/256, 256, 0, stream>>>(
        w_main, w_off, w_msk, wt, wb);

    conv27_kernel<<<NPIX/256, 256, 0, stream>>>(xt, wb, b_off, b_msk, om);

    deform_kernel<<<NPIX/64, 256, 0, stream>>>(xt, om, wt, out);
}